// Round 3
// baseline (7658.659 us; speedup 1.0000x reference)
//
#include <hip/hip_runtime.h>
#include <math.h>

#define N_LIT 200000
#define N_CLS 800000
#define NEDGE 2400000
#define NVAR  (N_LIT / 2)

__device__ __forceinline__ float silu_f(float x) { return x / (1.0f + expf(-x)); }

// bf16 <-> f32 helpers (self-contained, RNE rounding)
__device__ __forceinline__ float bf2f(unsigned short u) {
    unsigned int x = ((unsigned int)u) << 16;
    return __uint_as_float(x);
}
__device__ __forceinline__ unsigned short f2bf(float f) {
    unsigned int x = __float_as_uint(f);
    unsigned int r = (x + 0x7fffu + ((x >> 16) & 1u)) >> 16;
    return (unsigned short)r;
}

// ---------------------------------------------------------------- diagnostics
__global__ void diag_kernel(float* __restrict__ out, int n, float val) {
    int i = blockIdx.x * blockDim.x + threadIdx.x;
    int stride = gridDim.x * blockDim.x;
    for (; i < n; i += stride) out[i] = val;
}

// ---------------------------------------------------------------- int utils
__global__ void zero_int4_kernel(int4* __restrict__ p, long n4) {
    long i = (long)blockIdx.x * blockDim.x + threadIdx.x;
    long stride = (long)gridDim.x * blockDim.x;
    for (; i < n4; i += stride) p[i] = make_int4(0, 0, 0, 0);
}

__global__ void copy_int_kernel(int* __restrict__ dst, const int* __restrict__ src, int n) {
    int i = blockIdx.x * blockDim.x + threadIdx.x;
    int stride = gridDim.x * blockDim.x;
    for (; i < n; i += stride) dst[i] = src[i];
}

// ---------------------------------------------------------------- degrees
__global__ void deg_kernel(const int* __restrict__ edge_lit, const int* __restrict__ edge_cls,
                           int* __restrict__ deg_lit, int* __restrict__ deg_cls) {
    int stride = gridDim.x * blockDim.x;
    for (int e = blockIdx.x * blockDim.x + threadIdx.x; e < NEDGE; e += stride) {
        atomicAdd(&deg_lit[edge_lit[e]], 1);
        atomicAdd(&deg_cls[edge_cls[e]], 1);
    }
}

__global__ void inv_deg_kernel(const int* __restrict__ deg, float* __restrict__ inv, int n) {
    int i = blockIdx.x * blockDim.x + threadIdx.x;
    if (i < n) {
        int d = deg[i];
        inv[i] = 1.0f / (float)(d > 0 ? d : 1);
    }
}

// ---------------------------------------------------------------- exclusive scan (3-pass)
__global__ void scan_partial_kernel(const int* __restrict__ in, int n, int* __restrict__ part) {
    __shared__ int sh[256];
    int b = blockIdx.x, t = threadIdx.x;
    int base = b * 1024 + t * 4;
    int s = 0;
    #pragma unroll
    for (int i = 0; i < 4; ++i) { int idx = base + i; if (idx < n) s += in[idx]; }
    sh[t] = s; __syncthreads();
    for (int off = 128; off > 0; off >>= 1) {
        if (t < off) sh[t] += sh[t + off];
        __syncthreads();
    }
    if (t == 0) part[b] = sh[0];
}

__global__ void scan_root_kernel(int* __restrict__ part, int nb) {
    __shared__ int sh[1024];
    int t = threadIdx.x;
    int v = (t < nb) ? part[t] : 0;
    sh[t] = v; __syncthreads();
    for (int off = 1; off < 1024; off <<= 1) {
        int add = (t >= off) ? sh[t - off] : 0;
        __syncthreads();
        sh[t] += add;
        __syncthreads();
    }
    if (t < nb) part[t] = sh[t] - v;   // exclusive block offsets
}

__global__ void scan_final_kernel(const int* __restrict__ in, const int* __restrict__ part,
                                  int* __restrict__ out, int n) {
    __shared__ int sh[256];
    int b = blockIdx.x, t = threadIdx.x;
    int base = b * 1024 + t * 4;
    int v[4]; int s = 0;
    #pragma unroll
    for (int i = 0; i < 4; ++i) { int idx = base + i; v[i] = (idx < n) ? in[idx] : 0; s += v[i]; }
    sh[t] = s; __syncthreads();
    for (int off = 1; off < 256; off <<= 1) {
        int add = (t >= off) ? sh[t - off] : 0;
        __syncthreads();
        sh[t] += add;
        __syncthreads();
    }
    int run = part[b] + sh[t] - s;   // exclusive prefix for this thread
    #pragma unroll
    for (int i = 0; i < 4; ++i) { int idx = base + i; if (idx < n) { out[idx] = run; run += v[i]; } }
}

__global__ void tail_kernel(int* __restrict__ rp_cls, int* __restrict__ rp_lit) {
    if (blockIdx.x == 0 && threadIdx.x == 0) {
        rp_cls[N_CLS] = NEDGE;
        rp_lit[N_LIT] = NEDGE;
    }
}

// ---------------------------------------------------------------- CSR fill
__global__ void fill_csr_kernel(const int* __restrict__ e_lit, const int* __restrict__ e_cls,
                                int* __restrict__ cur_cls, int* __restrict__ cur_lit,
                                int* __restrict__ lit_by_cls, int* __restrict__ cls_by_lit) {
    int stride = gridDim.x * blockDim.x;
    for (int e = blockIdx.x * blockDim.x + threadIdx.x; e < NEDGE; e += stride) {
        int l = e_lit[e], c = e_cls[e];
        int p = atomicAdd(&cur_cls[c], 1); lit_by_cls[p] = l;
        int q = atomicAdd(&cur_lit[l], 1); cls_by_lit[q] = c;
    }
}

// ---------------------------------------------------------------- encoder
// h = silu(x @ w1 + b1) @ w2 + b2 ; lit rows -> fp32 h_lit, cls rows -> bf16 h_cls
__global__ __launch_bounds__(256) void encoder_kernel(
    const float* __restrict__ x_lit, const float* __restrict__ x_cls,
    const float* __restrict__ w1, const float* __restrict__ b1,
    const float* __restrict__ w2, const float* __restrict__ b2,
    float* __restrict__ h_lit, unsigned short* __restrict__ h_cls) {
    __shared__ float w1_s[4 * 64];
    __shared__ float b1_s[64];
    __shared__ float w2_s[64 * 64];
    __shared__ float b2_s[64];
    __shared__ float xs[16 * 4];
    __shared__ float hid_s[16 * 64];
    int t = threadIdx.x;
    w1_s[t] = w1[t];
    if (t < 64) { b1_s[t] = b1[t]; b2_s[t] = b2[t]; }
    for (int i = t; i < 64 * 64; i += 256) w2_s[i] = w2[i];
    __syncthreads();
    const int ntiles = (N_LIT + N_CLS) / 16;   // 62500, exact
    int w = t >> 6, j = t & 63;
    for (int tile = blockIdx.x; tile < ntiles; tile += gridDim.x) {
        int row0 = tile * 16;
        if (t < 64) {
            int r = t >> 2, k = t & 3;
            int row = row0 + r;
            xs[t] = (row < N_LIT) ? x_lit[row * 4 + k] : x_cls[(row - N_LIT) * 4 + k];
        }
        __syncthreads();
        #pragma unroll
        for (int rr = 0; rr < 4; ++rr) {
            int r = w * 4 + rr;
            float acc = b1_s[j];
            #pragma unroll
            for (int k = 0; k < 4; ++k) acc += xs[r * 4 + k] * w1_s[k * 64 + j];
            hid_s[r * 64 + j] = silu_f(acc);
        }
        __syncthreads();
        float acc0 = b2_s[j], acc1 = b2_s[j], acc2 = b2_s[j], acc3 = b2_s[j];
        const float* r0 = &hid_s[(w * 4 + 0) * 64];
        const float* r1 = &hid_s[(w * 4 + 1) * 64];
        const float* r2 = &hid_s[(w * 4 + 2) * 64];
        const float* r3 = &hid_s[(w * 4 + 3) * 64];
        #pragma unroll 4
        for (int k = 0; k < 64; k += 4) {
            float w0 = w2_s[k * 64 + j], w1v = w2_s[(k + 1) * 64 + j];
            float w2v = w2_s[(k + 2) * 64 + j], w3v = w2_s[(k + 3) * 64 + j];
            float4 a;
            a = *(const float4*)(r0 + k); acc0 += a.x * w0 + a.y * w1v + a.z * w2v + a.w * w3v;
            a = *(const float4*)(r1 + k); acc1 += a.x * w0 + a.y * w1v + a.z * w2v + a.w * w3v;
            a = *(const float4*)(r2 + k); acc2 += a.x * w0 + a.y * w1v + a.z * w2v + a.w * w3v;
            a = *(const float4*)(r3 + k); acc3 += a.x * w0 + a.y * w1v + a.z * w2v + a.w * w3v;
        }
        int row = row0 + w * 4;
        #pragma unroll
        for (int rr = 0; rr < 4; ++rr) {
            float v = (rr == 0) ? acc0 : (rr == 1) ? acc1 : (rr == 2) ? acc2 : acc3;
            int rw = row + rr;
            if (rw < N_LIT) h_lit[(size_t)rw * 64 + j] = v;
            else            h_cls[(size_t)(rw - N_LIT) * 64 + j] = f2bf(v);
        }
        __syncthreads();
    }
}

// ---------------------------------------------------------------- X = h_lit @ Wc_bot (fp32 -> bf16)
__global__ __launch_bounds__(256) void gemmX_kernel(
    const float* __restrict__ in, const float* __restrict__ W,
    unsigned short* __restrict__ out) {
    __shared__ float Ws[64 * 64];
    __shared__ float rs[16 * 64];
    int t = threadIdx.x;
    for (int i = t; i < 64 * 64; i += 256) Ws[i] = W[i];
    __syncthreads();
    const int ntiles = N_LIT / 16;   // 12500
    int w = t >> 6, j = t & 63;
    for (int tile = blockIdx.x; tile < ntiles; tile += gridDim.x) {
        int row0 = tile * 16;
        for (int i = t; i < 1024; i += 256) rs[i] = in[(size_t)row0 * 64 + i];
        __syncthreads();
        float acc0 = 0.f, acc1 = 0.f, acc2 = 0.f, acc3 = 0.f;
        const float* r0 = &rs[(w * 4 + 0) * 64];
        const float* r1 = &rs[(w * 4 + 1) * 64];
        const float* r2 = &rs[(w * 4 + 2) * 64];
        const float* r3 = &rs[(w * 4 + 3) * 64];
        #pragma unroll 4
        for (int k = 0; k < 64; k += 4) {
            float w0 = Ws[k * 64 + j], w1v = Ws[(k + 1) * 64 + j];
            float w2v = Ws[(k + 2) * 64 + j], w3v = Ws[(k + 3) * 64 + j];
            float4 a;
            a = *(const float4*)(r0 + k); acc0 += a.x * w0 + a.y * w1v + a.z * w2v + a.w * w3v;
            a = *(const float4*)(r1 + k); acc1 += a.x * w0 + a.y * w1v + a.z * w2v + a.w * w3v;
            a = *(const float4*)(r2 + k); acc2 += a.x * w0 + a.y * w1v + a.z * w2v + a.w * w3v;
            a = *(const float4*)(r3 + k); acc3 += a.x * w0 + a.y * w1v + a.z * w2v + a.w * w3v;
        }
        int row = row0 + w * 4;
        out[(size_t)(row + 0) * 64 + j] = f2bf(acc0);
        out[(size_t)(row + 1) * 64 + j] = f2bf(acc1);
        out[(size_t)(row + 2) * 64 + j] = f2bf(acc2);
        out[(size_t)(row + 3) * 64 + j] = f2bf(acc3);
        __syncthreads();
    }
}

// ---------------------------------------------------------------- clause update (fused gather, in-place bf16)
// h_cls[c] = (silu?(h_cls[c]) @ Wc_top + bc) + inv[c] * sum_{e in row c} X[lit[e]]
__global__ __launch_bounds__(256) void cls_update_kernel(
    unsigned short* __restrict__ h_cls, const unsigned short* __restrict__ X,
    const int* __restrict__ rp, const int* __restrict__ lits,
    const float* __restrict__ inv_deg, const float* __restrict__ W,
    const float* __restrict__ b, int silu_in) {
    __shared__ float Ws[64 * 64];
    __shared__ float bs[64];
    __shared__ float rs[16 * 64];
    int t = threadIdx.x;
    for (int i = t; i < 64 * 64; i += 256) Ws[i] = W[i];
    if (t < 64) bs[t] = b[t];
    __syncthreads();
    const int ntiles = N_CLS / 16;   // 50000
    int w = t >> 6, j = t & 63;
    for (int tile = blockIdx.x; tile < ntiles; tile += gridDim.x) {
        int row0 = tile * 16;
        for (int i = t; i < 1024; i += 256) {
            float v = bf2f(h_cls[(size_t)row0 * 64 + i]);
            rs[i] = silu_in ? silu_f(v) : v;
        }
        __syncthreads();
        float acc0 = bs[j], acc1 = bs[j], acc2 = bs[j], acc3 = bs[j];
        const float* r0 = &rs[(w * 4 + 0) * 64];
        const float* r1 = &rs[(w * 4 + 1) * 64];
        const float* r2 = &rs[(w * 4 + 2) * 64];
        const float* r3 = &rs[(w * 4 + 3) * 64];
        #pragma unroll 4
        for (int k = 0; k < 64; k += 4) {
            float w0 = Ws[k * 64 + j], w1v = Ws[(k + 1) * 64 + j];
            float w2v = Ws[(k + 2) * 64 + j], w3v = Ws[(k + 3) * 64 + j];
            float4 a;
            a = *(const float4*)(r0 + k); acc0 += a.x * w0 + a.y * w1v + a.z * w2v + a.w * w3v;
            a = *(const float4*)(r1 + k); acc1 += a.x * w0 + a.y * w1v + a.z * w2v + a.w * w3v;
            a = *(const float4*)(r2 + k); acc2 += a.x * w0 + a.y * w1v + a.z * w2v + a.w * w3v;
            a = *(const float4*)(r3 + k); acc3 += a.x * w0 + a.y * w1v + a.z * w2v + a.w * w3v;
        }
        // message gather: wave-uniform edge loop, lanes j=0..63 coalesced
        #pragma unroll
        for (int rr = 0; rr < 4; ++rr) {
            int row = row0 + w * 4 + rr;
            int e0 = rp[row], e1 = rp[row + 1];
            float g = 0.f;
            for (int e = e0; e < e1; ++e)
                g += bf2f(X[(size_t)lits[e] * 64 + j]);
            g *= inv_deg[row];
            if (rr == 0) acc0 += g; else if (rr == 1) acc1 += g;
            else if (rr == 2) acc2 += g; else acc3 += g;
        }
        int row = row0 + w * 4;
        h_cls[(size_t)(row + 0) * 64 + j] = f2bf(acc0);
        h_cls[(size_t)(row + 1) * 64 + j] = f2bf(acc1);
        h_cls[(size_t)(row + 2) * 64 + j] = f2bf(acc2);
        h_cls[(size_t)(row + 3) * 64 + j] = f2bf(acc3);
        __syncthreads();
    }
}

// ---------------------------------------------------------------- literal update (fused gather, in-place fp32)
// h[row] = silu([h[row], inv*sum silu(h_cls[nbr]), h[row^1]] @ W + b)
__global__ __launch_bounds__(256) void lit_update_kernel(
    float* __restrict__ h, const unsigned short* __restrict__ h_cls,
    const int* __restrict__ rp, const int* __restrict__ clss,
    const float* __restrict__ inv_deg, const float* __restrict__ W,
    const float* __restrict__ b) {
    __shared__ float Ws[192 * 64];   // 48 KB
    __shared__ float bs[64];
    __shared__ float rs[16 * 192];   // 12 KB
    int t = threadIdx.x;
    for (int i = t; i < 192 * 64; i += 256) Ws[i] = W[i];
    if (t < 64) bs[t] = b[t];
    __syncthreads();
    const int ntiles = N_LIT / 16;   // 12500
    int w = t >> 6, j = t & 63;
    for (int tile = blockIdx.x; tile < ntiles; tile += gridDim.x) {
        int row0 = tile * 16;
        // segments A (own) and C (flip partner, same tile)
        for (int i = t; i < 1024; i += 256) {
            int r = i >> 6, j2 = i & 63;
            int row = row0 + r;
            rs[r * 192 + j2]       = h[(size_t)row * 64 + j2];
            rs[r * 192 + 128 + j2] = h[(size_t)(row ^ 1) * 64 + j2];
        }
        // segment B: gather mean of silu(h_cls[nbrs]); wave-uniform edge loop
        for (int i = t; i < 1024; i += 256) {
            int r = i >> 6, j2 = i & 63;
            int row = row0 + r;
            int e0 = rp[row], e1 = rp[row + 1];
            float g = 0.f;
            for (int e = e0; e < e1; ++e)
                g += silu_f(bf2f(h_cls[(size_t)clss[e] * 64 + j2]));
            rs[r * 192 + 64 + j2] = g * inv_deg[row];
        }
        __syncthreads();
        float acc0 = bs[j], acc1 = bs[j], acc2 = bs[j], acc3 = bs[j];
        const float* r0 = &rs[(w * 4 + 0) * 192];
        const float* r1 = &rs[(w * 4 + 1) * 192];
        const float* r2 = &rs[(w * 4 + 2) * 192];
        const float* r3 = &rs[(w * 4 + 3) * 192];
        #pragma unroll 4
        for (int k = 0; k < 192; k += 4) {
            float w0 = Ws[k * 64 + j], w1v = Ws[(k + 1) * 64 + j];
            float w2v = Ws[(k + 2) * 64 + j], w3v = Ws[(k + 3) * 64 + j];
            float4 a;
            a = *(const float4*)(r0 + k); acc0 += a.x * w0 + a.y * w1v + a.z * w2v + a.w * w3v;
            a = *(const float4*)(r1 + k); acc1 += a.x * w0 + a.y * w1v + a.z * w2v + a.w * w3v;
            a = *(const float4*)(r2 + k); acc2 += a.x * w0 + a.y * w1v + a.z * w2v + a.w * w3v;
            a = *(const float4*)(r3 + k); acc3 += a.x * w0 + a.y * w1v + a.z * w2v + a.w * w3v;
        }
        int row = row0 + w * 4;
        h[(size_t)(row + 0) * 64 + j] = silu_f(acc0);
        h[(size_t)(row + 1) * 64 + j] = silu_f(acc1);
        h[(size_t)(row + 2) * 64 + j] = silu_f(acc2);
        h[(size_t)(row + 3) * 64 + j] = silu_f(acc3);
        __syncthreads();
    }
}

// ---------------------------------------------------------------- readout stage 1 (fp32 -> bf16 hid)
__global__ __launch_bounds__(256) void var_hidden_kernel(
    const float* __restrict__ h_var, const float* __restrict__ W,
    const float* __restrict__ b, int colofs, unsigned short* __restrict__ hid) {
    __shared__ float Ws[128 * 64];
    __shared__ float bs[64];
    __shared__ float rs[16 * 128];
    int t = threadIdx.x;
    for (int i = t; i < 128 * 64; i += 256) {
        int k = i >> 6, j = i & 63;
        Ws[i] = W[k * 128 + colofs + j];
    }
    if (t < 64) bs[t] = b[colofs + t];
    __syncthreads();
    const int ntiles = NVAR / 16;   // 6250
    int w = t >> 6, j = t & 63;
    for (int tile = blockIdx.x; tile < ntiles; tile += gridDim.x) {
        int row0 = tile * 16;
        for (int i = t; i < 2048; i += 256) rs[i] = h_var[(size_t)row0 * 128 + i];
        __syncthreads();
        float acc0 = bs[j], acc1 = bs[j], acc2 = bs[j], acc3 = bs[j];
        const float* r0 = &rs[(w * 4 + 0) * 128];
        const float* r1 = &rs[(w * 4 + 1) * 128];
        const float* r2 = &rs[(w * 4 + 2) * 128];
        const float* r3 = &rs[(w * 4 + 3) * 128];
        #pragma unroll 4
        for (int k = 0; k < 128; k += 4) {
            float w0 = Ws[k * 64 + j], w1v = Ws[(k + 1) * 64 + j];
            float w2v = Ws[(k + 2) * 64 + j], w3v = Ws[(k + 3) * 64 + j];
            float4 a;
            a = *(const float4*)(r0 + k); acc0 += a.x * w0 + a.y * w1v + a.z * w2v + a.w * w3v;
            a = *(const float4*)(r1 + k); acc1 += a.x * w0 + a.y * w1v + a.z * w2v + a.w * w3v;
            a = *(const float4*)(r2 + k); acc2 += a.x * w0 + a.y * w1v + a.z * w2v + a.w * w3v;
            a = *(const float4*)(r3 + k); acc3 += a.x * w0 + a.y * w1v + a.z * w2v + a.w * w3v;
        }
        int row = row0 + w * 4;
        hid[(size_t)(row + 0) * 128 + colofs + j] = f2bf(silu_f(acc0));
        hid[(size_t)(row + 1) * 128 + colofs + j] = f2bf(silu_f(acc1));
        hid[(size_t)(row + 2) * 128 + colofs + j] = f2bf(silu_f(acc2));
        hid[(size_t)(row + 3) * 128 + colofs + j] = f2bf(silu_f(acc3));
        __syncthreads();
    }
}

// ---------------------------------------------------------------- readout stage 2
__global__ __launch_bounds__(256) void out2_kernel(
    const unsigned short* __restrict__ hid, const float* __restrict__ w2,
    const float* __restrict__ b2, float* __restrict__ out) {
    int nw = (gridDim.x * blockDim.x) >> 6;
    int wid = (blockIdx.x * blockDim.x + threadIdx.x) >> 6;
    int lane = threadIdx.x & 63;
    float w00 = w2[lane * 2 + 0], w01 = w2[lane * 2 + 1];
    float w10 = w2[(lane + 64) * 2 + 0], w11 = w2[(lane + 64) * 2 + 1];
    for (int row = wid; row < NVAR; row += nw) {
        float h0 = bf2f(hid[(size_t)row * 128 + lane]);
        float h1 = bf2f(hid[(size_t)row * 128 + 64 + lane]);
        float p0 = h0 * w00 + h1 * w10;
        float p1 = h0 * w01 + h1 * w11;
        #pragma unroll
        for (int off = 32; off > 0; off >>= 1) {
            p0 += __shfl_down(p0, off);
            p1 += __shfl_down(p1, off);
        }
        if (lane == 0) {
            out[(size_t)row * 2 + 0] = p0 + b2[0];
            out[(size_t)row * 2 + 1] = p1 + b2[1];
        }
    }
}

// ---------------------------------------------------------------- launch
extern "C" void kernel_launch(void* const* d_in, const int* in_sizes, int n_in,
                              void* d_out, int out_size, void* d_ws, size_t ws_size,
                              hipStream_t stream) {
    const float* x_lit  = (const float*)d_in[0];
    const float* x_cls  = (const float*)d_in[1];
    const int* edge_lit = (const int*)d_in[2];
    const int* edge_cls = (const int*)d_in[3];
    const float* enc_w1 = (const float*)d_in[4];
    const float* enc_b1 = (const float*)d_in[5];
    const float* enc_w2 = (const float*)d_in[6];
    const float* enc_b2 = (const float*)d_in[7];
    const float* Wc     = (const float*)d_in[8];    // [4][128][64]
    const float* bc     = (const float*)d_in[9];
    const float* Wl     = (const float*)d_in[10];   // [4][192][64]
    const float* bl     = (const float*)d_in[11];
    const float* out_w1 = (const float*)d_in[12];   // [128][128]
    const float* out_b1 = (const float*)d_in[13];
    const float* out_w2 = (const float*)d_in[14];   // [128][2]
    const float* out_b2 = (const float*)d_in[15];
    float* y = (float*)d_out;

    // ---- workspace carve (each region 256B aligned), ~211 MB total ----
    const size_t SZ_HLIT = (size_t)N_LIT * 64;   // 12.8M elems
    const size_t SZ_HCLS = (size_t)N_CLS * 64;   // 51.2M elems
    char* p = (char*)d_ws;
    auto take = [&](size_t bytes) -> char* {
        char* r = p; p += (bytes + 255) & ~(size_t)255; return r;
    };
    float*          h_lit      = (float*)take(SZ_HLIT * 4);            // 51.2 MB
    unsigned short* h_cls      = (unsigned short*)take(SZ_HCLS * 2);   // 102.4 MB
    unsigned short* X          = (unsigned short*)take(SZ_HLIT * 2);   // 25.6 MB (msgs / readout hid)
    float*          inv_cls    = (float*)take((size_t)N_CLS * 4);
    float*          inv_lit    = (float*)take((size_t)N_LIT * 4);
    int*            row_ptr_cls= (int*)take((size_t)(N_CLS + 1) * 4);
    int*            row_ptr_lit= (int*)take((size_t)(N_LIT + 1) * 4);
    int*            cur_cls    = (int*)take((size_t)(N_CLS + N_LIT) * 4); // contiguous pair
    int*            cur_lit    = cur_cls + N_CLS;
    int*            lit_by_cls = (int*)take((size_t)NEDGE * 4);
    int*            cls_by_lit = (int*)take((size_t)NEDGE * 4);
    int*            partA      = (int*)take(1024 * 4);
    int*            partB      = (int*)take(1024 * 4);
    size_t need = (size_t)(p - (char*)d_ws);

    dim3 B(256);

    if (ws_size < need) {
        // diagnostic: don't touch d_ws; report ws_size (MB) through the output
        float mb = (float)((double)ws_size / (1024.0 * 1024.0));
        diag_kernel<<<256, B, 0, stream>>>(y, out_size, mb);
        return;
    }

    // ---- CSR build (re-poisoned ws -> rebuild every call) ----
    zero_int4_kernel<<<512, B, 0, stream>>>((int4*)cur_cls, (long)(N_CLS + N_LIT) / 4);
    deg_kernel<<<2048, B, 0, stream>>>(edge_lit, edge_cls, cur_lit, cur_cls);
    inv_deg_kernel<<<(N_CLS + 255) / 256, B, 0, stream>>>(cur_cls, inv_cls, N_CLS);
    inv_deg_kernel<<<(N_LIT + 255) / 256, B, 0, stream>>>(cur_lit, inv_lit, N_LIT);
    int nbc = (N_CLS + 1023) / 1024;   // 782
    int nbl = (N_LIT + 1023) / 1024;   // 196
    scan_partial_kernel<<<nbc, B, 0, stream>>>(cur_cls, N_CLS, partA);
    scan_root_kernel<<<1, 1024, 0, stream>>>(partA, nbc);
    scan_final_kernel<<<nbc, B, 0, stream>>>(cur_cls, partA, row_ptr_cls, N_CLS);
    scan_partial_kernel<<<nbl, B, 0, stream>>>(cur_lit, N_LIT, partB);
    scan_root_kernel<<<1, 1024, 0, stream>>>(partB, nbl);
    scan_final_kernel<<<nbl, B, 0, stream>>>(cur_lit, partB, row_ptr_lit, N_LIT);
    tail_kernel<<<1, 64, 0, stream>>>(row_ptr_cls, row_ptr_lit);
    copy_int_kernel<<<1024, B, 0, stream>>>(cur_cls, row_ptr_cls, N_CLS);
    copy_int_kernel<<<512, B, 0, stream>>>(cur_lit, row_ptr_lit, N_LIT);
    fill_csr_kernel<<<2048, B, 0, stream>>>(edge_lit, edge_cls, cur_cls, cur_lit,
                                            lit_by_cls, cls_by_lit);

    // ---- encoder ----
    encoder_kernel<<<4096, B, 0, stream>>>(x_lit, x_cls, enc_w1, enc_b1, enc_w2, enc_b2,
                                           h_lit, h_cls);
    // state: h_lit post-activation fp32; h_cls pre-activation bf16 (encoder output = final,
    // consumed raw at layer 0; layers l>0 apply silu on read)

    for (int l = 0; l < 4; ++l) {
        const float* Wc_l = Wc + (size_t)l * 128 * 64;
        const float* Wl_l = Wl + (size_t)l * 192 * 64;
        gemmX_kernel<<<4096, B, 0, stream>>>(h_lit, Wc_l + 64 * 64, X);
        cls_update_kernel<<<4096, B, 0, stream>>>(h_cls, X, row_ptr_cls, lit_by_cls,
                                                  inv_cls, Wc_l, bc + l * 64, l > 0);
        lit_update_kernel<<<4096, B, 0, stream>>>(h_lit, h_cls, row_ptr_lit, cls_by_lit,
                                                  inv_lit, Wl_l, bl + l * 64);
    }

    // ---- readout (hid reuses X: 100000*128 bf16 = 12.8M elems, exact fit) ----
    var_hidden_kernel<<<4096, B, 0, stream>>>(h_lit, out_w1, out_b1, 0, X);
    var_hidden_kernel<<<4096, B, 0, stream>>>(h_lit, out_w1, out_b1, 64, X);
    out2_kernel<<<2048, B, 0, stream>>>(X, out_w2, out_b2, y);
}

// Round 4
// 4800.059 us; speedup vs baseline: 1.5955x; 1.5955x over previous
//
#include <hip/hip_runtime.h>
#include <math.h>

#define N_LIT 200000
#define N_CLS 800000
#define NEDGE 2400000
#define NVAR  (N_LIT / 2)

__device__ __forceinline__ float silu_f(float x) { return x / (1.0f + expf(-x)); }

// bf16 <-> f32 helpers (self-contained, RNE rounding)
__device__ __forceinline__ float bf2f(unsigned short u) {
    unsigned int x = ((unsigned int)u) << 16;
    return __uint_as_float(x);
}
__device__ __forceinline__ unsigned short f2bf(float f) {
    unsigned int x = __float_as_uint(f);
    unsigned int r = (x + 0x7fffu + ((x >> 16) & 1u)) >> 16;
    return (unsigned short)r;
}

// ---------------------------------------------------------------- diagnostics
__global__ void diag_kernel(float* __restrict__ out, int n, float val) {
    int i = blockIdx.x * blockDim.x + threadIdx.x;
    int stride = gridDim.x * blockDim.x;
    for (; i < n; i += stride) out[i] = val;
}

// ---------------------------------------------------------------- int utils
__global__ void zero_int4_kernel(int4* __restrict__ p, long n4) {
    long i = (long)blockIdx.x * blockDim.x + threadIdx.x;
    long stride = (long)gridDim.x * blockDim.x;
    for (; i < n4; i += stride) p[i] = make_int4(0, 0, 0, 0);
}

__global__ void copy_int_kernel(int* __restrict__ dst, const int* __restrict__ src, int n) {
    int i = blockIdx.x * blockDim.x + threadIdx.x;
    int stride = gridDim.x * blockDim.x;
    for (; i < n; i += stride) dst[i] = src[i];
}

// ---------------------------------------------------------------- degrees
__global__ void deg_kernel(const int* __restrict__ edge_lit, const int* __restrict__ edge_cls,
                           int* __restrict__ deg_lit, int* __restrict__ deg_cls) {
    int stride = gridDim.x * blockDim.x;
    for (int e = blockIdx.x * blockDim.x + threadIdx.x; e < NEDGE; e += stride) {
        atomicAdd(&deg_lit[edge_lit[e]], 1);
        atomicAdd(&deg_cls[edge_cls[e]], 1);
    }
}

__global__ void inv_deg_kernel(const int* __restrict__ deg, float* __restrict__ inv, int n) {
    int i = blockIdx.x * blockDim.x + threadIdx.x;
    if (i < n) {
        int d = deg[i];
        inv[i] = 1.0f / (float)(d > 0 ? d : 1);
    }
}

// ---------------------------------------------------------------- exclusive scan (3-pass)
__global__ void scan_partial_kernel(const int* __restrict__ in, int n, int* __restrict__ part) {
    __shared__ int sh[256];
    int b = blockIdx.x, t = threadIdx.x;
    int base = b * 1024 + t * 4;
    int s = 0;
    #pragma unroll
    for (int i = 0; i < 4; ++i) { int idx = base + i; if (idx < n) s += in[idx]; }
    sh[t] = s; __syncthreads();
    for (int off = 128; off > 0; off >>= 1) {
        if (t < off) sh[t] += sh[t + off];
        __syncthreads();
    }
    if (t == 0) part[b] = sh[0];
}

__global__ void scan_root_kernel(int* __restrict__ part, int nb) {
    __shared__ int sh[1024];
    int t = threadIdx.x;
    int v = (t < nb) ? part[t] : 0;
    sh[t] = v; __syncthreads();
    for (int off = 1; off < 1024; off <<= 1) {
        int add = (t >= off) ? sh[t - off] : 0;
        __syncthreads();
        sh[t] += add;
        __syncthreads();
    }
    if (t < nb) part[t] = sh[t] - v;   // exclusive block offsets
}

__global__ void scan_final_kernel(const int* __restrict__ in, const int* __restrict__ part,
                                  int* __restrict__ out, int n) {
    __shared__ int sh[256];
    int b = blockIdx.x, t = threadIdx.x;
    int base = b * 1024 + t * 4;
    int v[4]; int s = 0;
    #pragma unroll
    for (int i = 0; i < 4; ++i) { int idx = base + i; v[i] = (idx < n) ? in[idx] : 0; s += v[i]; }
    sh[t] = s; __syncthreads();
    for (int off = 1; off < 256; off <<= 1) {
        int add = (t >= off) ? sh[t - off] : 0;
        __syncthreads();
        sh[t] += add;
        __syncthreads();
    }
    int run = part[b] + sh[t] - s;   // exclusive prefix for this thread
    #pragma unroll
    for (int i = 0; i < 4; ++i) { int idx = base + i; if (idx < n) { out[idx] = run; run += v[i]; } }
}

__global__ void tail_kernel(int* __restrict__ rp_cls, int* __restrict__ rp_lit) {
    if (blockIdx.x == 0 && threadIdx.x == 0) {
        rp_cls[N_CLS] = NEDGE;
        rp_lit[N_LIT] = NEDGE;
    }
}

// ---------------------------------------------------------------- CSR fill
__global__ void fill_csr_kernel(const int* __restrict__ e_lit, const int* __restrict__ e_cls,
                                int* __restrict__ cur_cls, int* __restrict__ cur_lit,
                                int* __restrict__ lit_by_cls, int* __restrict__ cls_by_lit) {
    int stride = gridDim.x * blockDim.x;
    for (int e = blockIdx.x * blockDim.x + threadIdx.x; e < NEDGE; e += stride) {
        int l = e_lit[e], c = e_cls[e];
        int p = atomicAdd(&cur_cls[c], 1); lit_by_cls[p] = l;
        int q = atomicAdd(&cur_lit[l], 1); cls_by_lit[q] = c;
    }
}

// ---------------------------------------------------------------- encoder
// h = silu(x @ w1 + b1) @ w2 + b2 ; lit rows -> fp32 h_lit, cls rows -> bf16 h_cls
__global__ __launch_bounds__(256) void encoder_kernel(
    const float* __restrict__ x_lit, const float* __restrict__ x_cls,
    const float* __restrict__ w1, const float* __restrict__ b1,
    const float* __restrict__ w2, const float* __restrict__ b2,
    float* __restrict__ h_lit, unsigned short* __restrict__ h_cls) {
    __shared__ float w1_s[4 * 64];
    __shared__ float b1_s[64];
    __shared__ float w2_s[64 * 64];
    __shared__ float b2_s[64];
    __shared__ float xs[16 * 4];
    __shared__ float hid_s[16 * 64];
    int t = threadIdx.x;
    w1_s[t] = w1[t];
    if (t < 64) { b1_s[t] = b1[t]; b2_s[t] = b2[t]; }
    for (int i = t; i < 64 * 64; i += 256) w2_s[i] = w2[i];
    __syncthreads();
    const int ntiles = (N_LIT + N_CLS) / 16;   // 62500, exact
    int w = t >> 6, j = t & 63;
    for (int tile = blockIdx.x; tile < ntiles; tile += gridDim.x) {
        int row0 = tile * 16;
        if (t < 64) {
            int r = t >> 2, k = t & 3;
            int row = row0 + r;
            xs[t] = (row < N_LIT) ? x_lit[row * 4 + k] : x_cls[(row - N_LIT) * 4 + k];
        }
        __syncthreads();
        #pragma unroll
        for (int rr = 0; rr < 4; ++rr) {
            int r = w * 4 + rr;
            float acc = b1_s[j];
            #pragma unroll
            for (int k = 0; k < 4; ++k) acc += xs[r * 4 + k] * w1_s[k * 64 + j];
            hid_s[r * 64 + j] = silu_f(acc);
        }
        __syncthreads();
        float acc0 = b2_s[j], acc1 = b2_s[j], acc2 = b2_s[j], acc3 = b2_s[j];
        const float* r0 = &hid_s[(w * 4 + 0) * 64];
        const float* r1 = &hid_s[(w * 4 + 1) * 64];
        const float* r2 = &hid_s[(w * 4 + 2) * 64];
        const float* r3 = &hid_s[(w * 4 + 3) * 64];
        #pragma unroll 4
        for (int k = 0; k < 64; k += 4) {
            float w0 = w2_s[k * 64 + j], w1v = w2_s[(k + 1) * 64 + j];
            float w2v = w2_s[(k + 2) * 64 + j], w3v = w2_s[(k + 3) * 64 + j];
            float4 a;
            a = *(const float4*)(r0 + k); acc0 += a.x * w0 + a.y * w1v + a.z * w2v + a.w * w3v;
            a = *(const float4*)(r1 + k); acc1 += a.x * w0 + a.y * w1v + a.z * w2v + a.w * w3v;
            a = *(const float4*)(r2 + k); acc2 += a.x * w0 + a.y * w1v + a.z * w2v + a.w * w3v;
            a = *(const float4*)(r3 + k); acc3 += a.x * w0 + a.y * w1v + a.z * w2v + a.w * w3v;
        }
        int row = row0 + w * 4;
        #pragma unroll
        for (int rr = 0; rr < 4; ++rr) {
            float v = (rr == 0) ? acc0 : (rr == 1) ? acc1 : (rr == 2) ? acc2 : acc3;
            int rw = row + rr;
            if (rw < N_LIT) h_lit[(size_t)rw * 64 + j] = v;
            else            h_cls[(size_t)(rw - N_LIT) * 64 + j] = f2bf(v);
        }
        __syncthreads();
    }
}

// ---------------------------------------------------------------- X = h_lit @ Wc_bot (fp32 -> bf16)
__global__ __launch_bounds__(256) void gemmX_kernel(
    const float* __restrict__ in, const float* __restrict__ W,
    unsigned short* __restrict__ out) {
    __shared__ float Ws[64 * 64];
    __shared__ float rs[16 * 64];
    int t = threadIdx.x;
    for (int i = t; i < 64 * 64; i += 256) Ws[i] = W[i];
    __syncthreads();
    const int ntiles = N_LIT / 16;   // 12500
    int w = t >> 6, j = t & 63;
    for (int tile = blockIdx.x; tile < ntiles; tile += gridDim.x) {
        int row0 = tile * 16;
        for (int i = t; i < 1024; i += 256) rs[i] = in[(size_t)row0 * 64 + i];
        __syncthreads();
        float acc0 = 0.f, acc1 = 0.f, acc2 = 0.f, acc3 = 0.f;
        const float* r0 = &rs[(w * 4 + 0) * 64];
        const float* r1 = &rs[(w * 4 + 1) * 64];
        const float* r2 = &rs[(w * 4 + 2) * 64];
        const float* r3 = &rs[(w * 4 + 3) * 64];
        #pragma unroll 4
        for (int k = 0; k < 64; k += 4) {
            float w0 = Ws[k * 64 + j], w1v = Ws[(k + 1) * 64 + j];
            float w2v = Ws[(k + 2) * 64 + j], w3v = Ws[(k + 3) * 64 + j];
            float4 a;
            a = *(const float4*)(r0 + k); acc0 += a.x * w0 + a.y * w1v + a.z * w2v + a.w * w3v;
            a = *(const float4*)(r1 + k); acc1 += a.x * w0 + a.y * w1v + a.z * w2v + a.w * w3v;
            a = *(const float4*)(r2 + k); acc2 += a.x * w0 + a.y * w1v + a.z * w2v + a.w * w3v;
            a = *(const float4*)(r3 + k); acc3 += a.x * w0 + a.y * w1v + a.z * w2v + a.w * w3v;
        }
        int row = row0 + w * 4;
        out[(size_t)(row + 0) * 64 + j] = f2bf(acc0);
        out[(size_t)(row + 1) * 64 + j] = f2bf(acc1);
        out[(size_t)(row + 2) * 64 + j] = f2bf(acc2);
        out[(size_t)(row + 3) * 64 + j] = f2bf(acc3);
        __syncthreads();
    }
}

// ---------------------------------------------------------------- clause update (fused gather, in-place bf16)
// h_cls[c] = (silu?(h_cls[c]) @ Wc_top + bc) + inv[c] * sum_{e in row c} X[lit[e]]
__global__ __launch_bounds__(256) void cls_update_kernel(
    unsigned short* __restrict__ h_cls, const unsigned short* __restrict__ X,
    const int* __restrict__ rp, const int* __restrict__ lits,
    const float* __restrict__ inv_deg, const float* __restrict__ W,
    const float* __restrict__ b, int silu_in) {
    __shared__ float Ws[64 * 64];
    __shared__ float bs[64];
    __shared__ float rs[16 * 64];
    int t = threadIdx.x;
    for (int i = t; i < 64 * 64; i += 256) Ws[i] = W[i];
    if (t < 64) bs[t] = b[t];
    __syncthreads();
    const int ntiles = N_CLS / 16;   // 50000
    int w = t >> 6, j = t & 63;
    for (int tile = blockIdx.x; tile < ntiles; tile += gridDim.x) {
        int row0 = tile * 16;
        for (int i = t; i < 1024; i += 256) {
            float v = bf2f(h_cls[(size_t)row0 * 64 + i]);
            rs[i] = silu_in ? silu_f(v) : v;
        }
        __syncthreads();
        float acc0 = bs[j], acc1 = bs[j], acc2 = bs[j], acc3 = bs[j];
        const float* r0 = &rs[(w * 4 + 0) * 64];
        const float* r1 = &rs[(w * 4 + 1) * 64];
        const float* r2 = &rs[(w * 4 + 2) * 64];
        const float* r3 = &rs[(w * 4 + 3) * 64];
        #pragma unroll 4
        for (int k = 0; k < 64; k += 4) {
            float w0 = Ws[k * 64 + j], w1v = Ws[(k + 1) * 64 + j];
            float w2v = Ws[(k + 2) * 64 + j], w3v = Ws[(k + 3) * 64 + j];
            float4 a;
            a = *(const float4*)(r0 + k); acc0 += a.x * w0 + a.y * w1v + a.z * w2v + a.w * w3v;
            a = *(const float4*)(r1 + k); acc1 += a.x * w0 + a.y * w1v + a.z * w2v + a.w * w3v;
            a = *(const float4*)(r2 + k); acc2 += a.x * w0 + a.y * w1v + a.z * w2v + a.w * w3v;
            a = *(const float4*)(r3 + k); acc3 += a.x * w0 + a.y * w1v + a.z * w2v + a.w * w3v;
        }
        // message gather: wave-uniform edge loop, lanes j=0..63 coalesced, 2-way MLP
        #pragma unroll
        for (int rr = 0; rr < 4; ++rr) {
            int row = row0 + w * 4 + rr;
            int e0 = rp[row], e1 = rp[row + 1];
            float g0 = 0.f, g1 = 0.f;
            int e = e0;
            for (; e + 1 < e1; e += 2) {
                int l0 = lits[e], l1 = lits[e + 1];
                g0 += bf2f(X[(size_t)l0 * 64 + j]);
                g1 += bf2f(X[(size_t)l1 * 64 + j]);
            }
            if (e < e1) g0 += bf2f(X[(size_t)lits[e] * 64 + j]);
            float g = (g0 + g1) * inv_deg[row];
            if (rr == 0) acc0 += g; else if (rr == 1) acc1 += g;
            else if (rr == 2) acc2 += g; else acc3 += g;
        }
        int row = row0 + w * 4;
        h_cls[(size_t)(row + 0) * 64 + j] = f2bf(acc0);
        h_cls[(size_t)(row + 1) * 64 + j] = f2bf(acc1);
        h_cls[(size_t)(row + 2) * 64 + j] = f2bf(acc2);
        h_cls[(size_t)(row + 3) * 64 + j] = f2bf(acc3);
        __syncthreads();
    }
}

// ---------------------------------------------------------------- lit-side gather (standalone, no LDS)
// m_out[row] = inv[row] * sum_{e in row} silu(h_cls[clss[e]])   (bf16 out)
// one wave per row, lane = channel; 2-way unrolled edge loop for MLP;
// no LDS + low VGPR -> high occupancy to hide random-gather latency
__global__ __launch_bounds__(256) void gather_lit_kernel(
    const unsigned short* __restrict__ h_cls, const int* __restrict__ rp,
    const int* __restrict__ clss, const float* __restrict__ inv_deg,
    unsigned short* __restrict__ m_out) {
    int nw = (gridDim.x * blockDim.x) >> 6;
    int wid = (blockIdx.x * blockDim.x + threadIdx.x) >> 6;
    int lane = threadIdx.x & 63;
    for (int row = wid; row < N_LIT; row += nw) {
        int e0 = rp[row], e1 = rp[row + 1];
        float g0 = 0.f, g1 = 0.f;
        int e = e0;
        for (; e + 1 < e1; e += 2) {
            int c0 = clss[e], c1 = clss[e + 1];
            float v0 = bf2f(h_cls[(size_t)c0 * 64 + lane]);
            float v1 = bf2f(h_cls[(size_t)c1 * 64 + lane]);
            g0 += silu_f(v0);
            g1 += silu_f(v1);
        }
        if (e < e1) g0 += silu_f(bf2f(h_cls[(size_t)clss[e] * 64 + lane]));
        m_out[(size_t)row * 64 + lane] = f2bf((g0 + g1) * inv_deg[row]);
    }
}

// ---------------------------------------------------------------- literal update (in-place fp32, streams m from X)
// h[row] = silu([h[row], m[row], h[row^1]] @ W + b)
__global__ __launch_bounds__(256) void lit_update_kernel(
    float* __restrict__ h, const unsigned short* __restrict__ m,
    const float* __restrict__ W, const float* __restrict__ b) {
    __shared__ float Ws[192 * 64];   // 48 KB
    __shared__ float bs[64];
    __shared__ float rs[16 * 192];   // 12 KB
    int t = threadIdx.x;
    for (int i = t; i < 192 * 64; i += 256) Ws[i] = W[i];
    if (t < 64) bs[t] = b[t];
    __syncthreads();
    const int ntiles = N_LIT / 16;   // 12500
    int w = t >> 6, j = t & 63;
    for (int tile = blockIdx.x; tile < ntiles; tile += gridDim.x) {
        int row0 = tile * 16;
        for (int i = t; i < 1024; i += 256) {
            int r = i >> 6, j2 = i & 63;
            int row = row0 + r;
            rs[r * 192 + j2]       = h[(size_t)row * 64 + j2];
            rs[r * 192 + 64 + j2]  = bf2f(m[(size_t)row * 64 + j2]);
            rs[r * 192 + 128 + j2] = h[(size_t)(row ^ 1) * 64 + j2];
        }
        __syncthreads();
        float acc0 = bs[j], acc1 = bs[j], acc2 = bs[j], acc3 = bs[j];
        const float* r0 = &rs[(w * 4 + 0) * 192];
        const float* r1 = &rs[(w * 4 + 1) * 192];
        const float* r2 = &rs[(w * 4 + 2) * 192];
        const float* r3 = &rs[(w * 4 + 3) * 192];
        #pragma unroll 4
        for (int k = 0; k < 192; k += 4) {
            float w0 = Ws[k * 64 + j], w1v = Ws[(k + 1) * 64 + j];
            float w2v = Ws[(k + 2) * 64 + j], w3v = Ws[(k + 3) * 64 + j];
            float4 a;
            a = *(const float4*)(r0 + k); acc0 += a.x * w0 + a.y * w1v + a.z * w2v + a.w * w3v;
            a = *(const float4*)(r1 + k); acc1 += a.x * w0 + a.y * w1v + a.z * w2v + a.w * w3v;
            a = *(const float4*)(r2 + k); acc2 += a.x * w0 + a.y * w1v + a.z * w2v + a.w * w3v;
            a = *(const float4*)(r3 + k); acc3 += a.x * w0 + a.y * w1v + a.z * w2v + a.w * w3v;
        }
        int row = row0 + w * 4;
        h[(size_t)(row + 0) * 64 + j] = silu_f(acc0);
        h[(size_t)(row + 1) * 64 + j] = silu_f(acc1);
        h[(size_t)(row + 2) * 64 + j] = silu_f(acc2);
        h[(size_t)(row + 3) * 64 + j] = silu_f(acc3);
        __syncthreads();
    }
}

// ---------------------------------------------------------------- readout stage 1 (fp32 -> bf16 hid)
__global__ __launch_bounds__(256) void var_hidden_kernel(
    const float* __restrict__ h_var, const float* __restrict__ W,
    const float* __restrict__ b, int colofs, unsigned short* __restrict__ hid) {
    __shared__ float Ws[128 * 64];
    __shared__ float bs[64];
    __shared__ float rs[16 * 128];
    int t = threadIdx.x;
    for (int i = t; i < 128 * 64; i += 256) {
        int k = i >> 6, j = i & 63;
        Ws[i] = W[k * 128 + colofs + j];
    }
    if (t < 64) bs[t] = b[colofs + t];
    __syncthreads();
    const int ntiles = NVAR / 16;   // 6250
    int w = t >> 6, j = t & 63;
    for (int tile = blockIdx.x; tile < ntiles; tile += gridDim.x) {
        int row0 = tile * 16;
        for (int i = t; i < 2048; i += 256) rs[i] = h_var[(size_t)row0 * 128 + i];
        __syncthreads();
        float acc0 = bs[j], acc1 = bs[j], acc2 = bs[j], acc3 = bs[j];
        const float* r0 = &rs[(w * 4 + 0) * 128];
        const float* r1 = &rs[(w * 4 + 1) * 128];
        const float* r2 = &rs[(w * 4 + 2) * 128];
        const float* r3 = &rs[(w * 4 + 3) * 128];
        #pragma unroll 4
        for (int k = 0; k < 128; k += 4) {
            float w0 = Ws[k * 64 + j], w1v = Ws[(k + 1) * 64 + j];
            float w2v = Ws[(k + 2) * 64 + j], w3v = Ws[(k + 3) * 64 + j];
            float4 a;
            a = *(const float4*)(r0 + k); acc0 += a.x * w0 + a.y * w1v + a.z * w2v + a.w * w3v;
            a = *(const float4*)(r1 + k); acc1 += a.x * w0 + a.y * w1v + a.z * w2v + a.w * w3v;
            a = *(const float4*)(r2 + k); acc2 += a.x * w0 + a.y * w1v + a.z * w2v + a.w * w3v;
            a = *(const float4*)(r3 + k); acc3 += a.x * w0 + a.y * w1v + a.z * w2v + a.w * w3v;
        }
        int row = row0 + w * 4;
        hid[(size_t)(row + 0) * 128 + colofs + j] = f2bf(silu_f(acc0));
        hid[(size_t)(row + 1) * 128 + colofs + j] = f2bf(silu_f(acc1));
        hid[(size_t)(row + 2) * 128 + colofs + j] = f2bf(silu_f(acc2));
        hid[(size_t)(row + 3) * 128 + colofs + j] = f2bf(silu_f(acc3));
        __syncthreads();
    }
}

// ---------------------------------------------------------------- readout stage 2
__global__ __launch_bounds__(256) void out2_kernel(
    const unsigned short* __restrict__ hid, const float* __restrict__ w2,
    const float* __restrict__ b2, float* __restrict__ out) {
    int nw = (gridDim.x * blockDim.x) >> 6;
    int wid = (blockIdx.x * blockDim.x + threadIdx.x) >> 6;
    int lane = threadIdx.x & 63;
    float w00 = w2[lane * 2 + 0], w01 = w2[lane * 2 + 1];
    float w10 = w2[(lane + 64) * 2 + 0], w11 = w2[(lane + 64) * 2 + 1];
    for (int row = wid; row < NVAR; row += nw) {
        float h0 = bf2f(hid[(size_t)row * 128 + lane]);
        float h1 = bf2f(hid[(size_t)row * 128 + 64 + lane]);
        float p0 = h0 * w00 + h1 * w10;
        float p1 = h0 * w01 + h1 * w11;
        #pragma unroll
        for (int off = 32; off > 0; off >>= 1) {
            p0 += __shfl_down(p0, off);
            p1 += __shfl_down(p1, off);
        }
        if (lane == 0) {
            out[(size_t)row * 2 + 0] = p0 + b2[0];
            out[(size_t)row * 2 + 1] = p1 + b2[1];
        }
    }
}

// ---------------------------------------------------------------- launch
extern "C" void kernel_launch(void* const* d_in, const int* in_sizes, int n_in,
                              void* d_out, int out_size, void* d_ws, size_t ws_size,
                              hipStream_t stream) {
    const float* x_lit  = (const float*)d_in[0];
    const float* x_cls  = (const float*)d_in[1];
    const int* edge_lit = (const int*)d_in[2];
    const int* edge_cls = (const int*)d_in[3];
    const float* enc_w1 = (const float*)d_in[4];
    const float* enc_b1 = (const float*)d_in[5];
    const float* enc_w2 = (const float*)d_in[6];
    const float* enc_b2 = (const float*)d_in[7];
    const float* Wc     = (const float*)d_in[8];    // [4][128][64]
    const float* bc     = (const float*)d_in[9];
    const float* Wl     = (const float*)d_in[10];   // [4][192][64]
    const float* bl     = (const float*)d_in[11];
    const float* out_w1 = (const float*)d_in[12];   // [128][128]
    const float* out_b1 = (const float*)d_in[13];
    const float* out_w2 = (const float*)d_in[14];   // [128][2]
    const float* out_b2 = (const float*)d_in[15];
    float* y = (float*)d_out;

    // ---- workspace carve (each region 256B aligned), ~211 MB total ----
    const size_t SZ_HLIT = (size_t)N_LIT * 64;   // 12.8M elems
    const size_t SZ_HCLS = (size_t)N_CLS * 64;   // 51.2M elems
    char* p = (char*)d_ws;
    auto take = [&](size_t bytes) -> char* {
        char* r = p; p += (bytes + 255) & ~(size_t)255; return r;
    };
    float*          h_lit      = (float*)take(SZ_HLIT * 4);            // 51.2 MB
    unsigned short* h_cls      = (unsigned short*)take(SZ_HCLS * 2);   // 102.4 MB
    unsigned short* X          = (unsigned short*)take(SZ_HLIT * 2);   // 25.6 MB (cls msgs / lit msgs / readout hid)
    float*          inv_cls    = (float*)take((size_t)N_CLS * 4);
    float*          inv_lit    = (float*)take((size_t)N_LIT * 4);
    int*            row_ptr_cls= (int*)take((size_t)(N_CLS + 1) * 4);
    int*            row_ptr_lit= (int*)take((size_t)(N_LIT + 1) * 4);
    int*            cur_cls    = (int*)take((size_t)(N_CLS + N_LIT) * 4); // contiguous pair
    int*            cur_lit    = cur_cls + N_CLS;
    int*            lit_by_cls = (int*)take((size_t)NEDGE * 4);
    int*            cls_by_lit = (int*)take((size_t)NEDGE * 4);
    int*            partA      = (int*)take(1024 * 4);
    int*            partB      = (int*)take(1024 * 4);
    size_t need = (size_t)(p - (char*)d_ws);

    dim3 B(256);

    if (ws_size < need) {
        float mb = (float)((double)ws_size / (1024.0 * 1024.0));
        diag_kernel<<<256, B, 0, stream>>>(y, out_size, mb);
        return;
    }

    // ---- CSR build (re-poisoned ws -> rebuild every call) ----
    zero_int4_kernel<<<512, B, 0, stream>>>((int4*)cur_cls, (long)(N_CLS + N_LIT) / 4);
    deg_kernel<<<2048, B, 0, stream>>>(edge_lit, edge_cls, cur_lit, cur_cls);
    inv_deg_kernel<<<(N_CLS + 255) / 256, B, 0, stream>>>(cur_cls, inv_cls, N_CLS);
    inv_deg_kernel<<<(N_LIT + 255) / 256, B, 0, stream>>>(cur_lit, inv_lit, N_LIT);
    int nbc = (N_CLS + 1023) / 1024;   // 782
    int nbl = (N_LIT + 1023) / 1024;   // 196
    scan_partial_kernel<<<nbc, B, 0, stream>>>(cur_cls, N_CLS, partA);
    scan_root_kernel<<<1, 1024, 0, stream>>>(partA, nbc);
    scan_final_kernel<<<nbc, B, 0, stream>>>(cur_cls, partA, row_ptr_cls, N_CLS);
    scan_partial_kernel<<<nbl, B, 0, stream>>>(cur_lit, N_LIT, partB);
    scan_root_kernel<<<1, 1024, 0, stream>>>(partB, nbl);
    scan_final_kernel<<<nbl, B, 0, stream>>>(cur_lit, partB, row_ptr_lit, N_LIT);
    tail_kernel<<<1, 64, 0, stream>>>(row_ptr_cls, row_ptr_lit);
    copy_int_kernel<<<1024, B, 0, stream>>>(cur_cls, row_ptr_cls, N_CLS);
    copy_int_kernel<<<512, B, 0, stream>>>(cur_lit, row_ptr_lit, N_LIT);
    fill_csr_kernel<<<2048, B, 0, stream>>>(edge_lit, edge_cls, cur_cls, cur_lit,
                                            lit_by_cls, cls_by_lit);

    // ---- encoder ----
    encoder_kernel<<<4096, B, 0, stream>>>(x_lit, x_cls, enc_w1, enc_b1, enc_w2, enc_b2,
                                           h_lit, h_cls);
    // state: h_lit post-activation fp32; h_cls pre-activation bf16 (encoder output = final,
    // consumed raw at layer 0; layers l>0 apply silu on read)

    for (int l = 0; l < 4; ++l) {
        const float* Wc_l = Wc + (size_t)l * 128 * 64;
        const float* Wl_l = Wl + (size_t)l * 192 * 64;
        gemmX_kernel<<<4096, B, 0, stream>>>(h_lit, Wc_l + 64 * 64, X);
        cls_update_kernel<<<4096, B, 0, stream>>>(h_cls, X, row_ptr_cls, lit_by_cls,
                                                  inv_cls, Wc_l, bc + l * 64, l > 0);
        // X's cls-msg contents are dead now; reuse it for lit msgs (bf16, exact fit)
        gather_lit_kernel<<<4096, B, 0, stream>>>(h_cls, row_ptr_lit, cls_by_lit,
                                                  inv_lit, X);
        lit_update_kernel<<<4096, B, 0, stream>>>(h_lit, X, Wl_l, bl + l * 64);
    }

    // ---- readout (hid reuses X: 100000*128 bf16 = 12.8M elems, exact fit) ----
    var_hidden_kernel<<<4096, B, 0, stream>>>(h_lit, out_w1, out_b1, 0, X);
    var_hidden_kernel<<<4096, B, 0, stream>>>(h_lit, out_w1, out_b1, 64, X);
    out2_kernel<<<2048, B, 0, stream>>>(X, out_w2, out_b2, y);
}

// Round 5
// 3129.260 us; speedup vs baseline: 2.4474x; 1.5339x over previous
//
#include <hip/hip_runtime.h>
#include <math.h>

#define N_LIT 200000
#define N_CLS 800000
#define NEDGE 2400000
#define NVAR  (N_LIT / 2)

typedef __attribute__((ext_vector_type(8))) short bf16x8;
typedef __attribute__((ext_vector_type(4))) float f32x4;

__device__ __forceinline__ float silu_f(float x) { return x / (1.0f + expf(-x)); }

__device__ __forceinline__ float bf2f(unsigned short u) {
    unsigned int x = ((unsigned int)u) << 16;
    return __uint_as_float(x);
}
__device__ __forceinline__ unsigned short f2bf(float f) {
    unsigned int x = __float_as_uint(f);
    unsigned int r = (x + 0x7fffu + ((x >> 16) & 1u)) >> 16;
    return (unsigned short)r;
}

// ---------------------------------------------------------------- diagnostics
__global__ void diag_kernel(float* __restrict__ out, int n, float val) {
    int i = blockIdx.x * blockDim.x + threadIdx.x;
    int stride = gridDim.x * blockDim.x;
    for (; i < n; i += stride) out[i] = val;
}

// ---------------------------------------------------------------- int utils
__global__ void zero_int4_kernel(int4* __restrict__ p, long n4) {
    long i = (long)blockIdx.x * blockDim.x + threadIdx.x;
    long stride = (long)gridDim.x * blockDim.x;
    for (; i < n4; i += stride) p[i] = make_int4(0, 0, 0, 0);
}

__global__ void copy_int_kernel(int* __restrict__ dst, const int* __restrict__ src, int n) {
    int i = blockIdx.x * blockDim.x + threadIdx.x;
    int stride = gridDim.x * blockDim.x;
    for (; i < n; i += stride) dst[i] = src[i];
}

// ---------------------------------------------------------------- degrees
__global__ void deg_kernel(const int* __restrict__ edge_lit, const int* __restrict__ edge_cls,
                           int* __restrict__ deg_lit, int* __restrict__ deg_cls) {
    int stride = gridDim.x * blockDim.x;
    for (int e = blockIdx.x * blockDim.x + threadIdx.x; e < NEDGE; e += stride) {
        atomicAdd(&deg_lit[edge_lit[e]], 1);
        atomicAdd(&deg_cls[edge_cls[e]], 1);
    }
}

__global__ void inv_deg_kernel(const int* __restrict__ deg, float* __restrict__ inv, int n) {
    int i = blockIdx.x * blockDim.x + threadIdx.x;
    if (i < n) {
        int d = deg[i];
        inv[i] = 1.0f / (float)(d > 0 ? d : 1);
    }
}

// ---------------------------------------------------------------- exclusive scan (3-pass)
__global__ void scan_partial_kernel(const int* __restrict__ in, int n, int* __restrict__ part) {
    __shared__ int sh[256];
    int b = blockIdx.x, t = threadIdx.x;
    int base = b * 1024 + t * 4;
    int s = 0;
    #pragma unroll
    for (int i = 0; i < 4; ++i) { int idx = base + i; if (idx < n) s += in[idx]; }
    sh[t] = s; __syncthreads();
    for (int off = 128; off > 0; off >>= 1) {
        if (t < off) sh[t] += sh[t + off];
        __syncthreads();
    }
    if (t == 0) part[b] = sh[0];
}

__global__ void scan_root_kernel(int* __restrict__ part, int nb) {
    __shared__ int sh[1024];
    int t = threadIdx.x;
    int v = (t < nb) ? part[t] : 0;
    sh[t] = v; __syncthreads();
    for (int off = 1; off < 1024; off <<= 1) {
        int add = (t >= off) ? sh[t - off] : 0;
        __syncthreads();
        sh[t] += add;
        __syncthreads();
    }
    if (t < nb) part[t] = sh[t] - v;   // exclusive block offsets
}

__global__ void scan_final_kernel(const int* __restrict__ in, const int* __restrict__ part,
                                  int* __restrict__ out, int n) {
    __shared__ int sh[256];
    int b = blockIdx.x, t = threadIdx.x;
    int base = b * 1024 + t * 4;
    int v[4]; int s = 0;
    #pragma unroll
    for (int i = 0; i < 4; ++i) { int idx = base + i; v[i] = (idx < n) ? in[idx] : 0; s += v[i]; }
    sh[t] = s; __syncthreads();
    for (int off = 1; off < 256; off <<= 1) {
        int add = (t >= off) ? sh[t - off] : 0;
        __syncthreads();
        sh[t] += add;
        __syncthreads();
    }
    int run = part[b] + sh[t] - s;
    #pragma unroll
    for (int i = 0; i < 4; ++i) { int idx = base + i; if (idx < n) { out[idx] = run; run += v[i]; } }
}

__global__ void tail_kernel(int* __restrict__ rp_cls, int* __restrict__ rp_lit) {
    if (blockIdx.x == 0 && threadIdx.x == 0) {
        rp_cls[N_CLS] = NEDGE;
        rp_lit[N_LIT] = NEDGE;
    }
}

// ---------------------------------------------------------------- CSR fill
__global__ void fill_csr_kernel(const int* __restrict__ e_lit, const int* __restrict__ e_cls,
                                int* __restrict__ cur_cls, int* __restrict__ cur_lit,
                                int* __restrict__ lit_by_cls, int* __restrict__ cls_by_lit) {
    int stride = gridDim.x * blockDim.x;
    for (int e = blockIdx.x * blockDim.x + threadIdx.x; e < NEDGE; e += stride) {
        int l = e_lit[e], c = e_cls[e];
        int p = atomicAdd(&cur_cls[c], 1); lit_by_cls[p] = l;
        int q = atomicAdd(&cur_lit[l], 1); cls_by_lit[q] = c;
    }
}

// ---------------------------------------------------------------- encoder (MFMA 2nd GEMM)
// h = silu(x @ w1 + b1) @ w2 + b2 ; lit rows -> fp32 h_lit, cls rows -> bf16 h_cls
// waves independent after weight staging; 16-row tile per wave.
__global__ __launch_bounds__(256, 4) void encoder_kernel(
    const float* __restrict__ x_lit, const float* __restrict__ x_cls,
    const float* __restrict__ w1, const float* __restrict__ b1,
    const float* __restrict__ w2, const float* __restrict__ b2,
    float* __restrict__ h_lit, unsigned short* __restrict__ h_cls) {
    __shared__ float w1s[4 * 64];
    __shared__ float b1s[64], b2s[64];
    __shared__ __align__(16) unsigned short Bp[8 * 64 * 8];   // 8 KB packed w2 frags
    __shared__ float xt[4][64];
    __shared__ float hs[4][16 * 68];                          // hid tile / D staging (pad 68)
    int t = threadIdx.x;
    w1s[t] = w1[t];
    if (t < 64) { b1s[t] = b1[t]; b2s[t] = b2[t]; }
    for (int idx = t; idx < 8 * 64 * 8; idx += 256) {
        int i = idx & 7, ln = (idx >> 3) & 63, fid = idx >> 9;
        int ks = fid >> 2, nt = fid & 3;
        int k = ks * 32 + ((ln >> 4) << 3) + i;
        int n = nt * 16 + (ln & 15);
        Bp[idx] = f2bf(w2[k * 64 + n]);
    }
    __syncthreads();
    int w = t >> 6, lane = t & 63;
    int c = lane & 15, q = lane >> 4;
    bf16x8 Bf[8];
    #pragma unroll
    for (int f = 0; f < 8; ++f) Bf[f] = *(const bf16x8*)&Bp[(f * 64 + lane) * 8];
    float* hw = hs[w];
    int nwaves = gridDim.x * 4;
    int wid = blockIdx.x * 4 + w;
    const int ntiles = (N_LIT + N_CLS) / 16;   // 62500; N_LIT%16==0 -> tiles never straddle
    for (int tile = wid; tile < ntiles; tile += nwaves) {
        int row0 = tile * 16;
        const float* xsrc = (row0 < N_LIT) ? x_lit + (size_t)row0 * 4
                                           : x_cls + (size_t)(row0 - N_LIT) * 4;
        xt[w][lane] = xsrc[lane];
        for (int r = 0; r < 16; ++r) {
            float pre = b1s[lane];
            #pragma unroll
            for (int k = 0; k < 4; ++k) pre += xt[w][r * 4 + k] * w1s[k * 64 + lane];
            hw[r * 68 + lane] = silu_f(pre);
        }
        bf16x8 A0, A1;
        const float* ap = &hw[c * 68 + q * 8];
        #pragma unroll
        for (int i = 0; i < 8; ++i) {
            A0[i] = (short)f2bf(ap[i]);
            A1[i] = (short)f2bf(ap[32 + i]);
        }
        f32x4 acc[4];
        #pragma unroll
        for (int nt = 0; nt < 4; ++nt) {
            float bv = b2s[nt * 16 + c];
            acc[nt] = (f32x4){bv, bv, bv, bv};
            acc[nt] = __builtin_amdgcn_mfma_f32_16x16x32_bf16(A0, Bf[nt], acc[nt], 0, 0, 0);
            acc[nt] = __builtin_amdgcn_mfma_f32_16x16x32_bf16(A1, Bf[4 + nt], acc[nt], 0, 0, 0);
        }
        #pragma unroll
        for (int nt = 0; nt < 4; ++nt)
            #pragma unroll
            for (int rg = 0; rg < 4; ++rg)
                hw[(q * 4 + rg) * 68 + nt * 16 + c] = acc[nt][rg];
        if (row0 < N_LIT) {
            for (int r = 0; r < 16; ++r)
                h_lit[(size_t)(row0 + r) * 64 + lane] = hw[r * 68 + lane];
        } else {
            for (int r = 0; r < 16; ++r)
                h_cls[(size_t)(row0 + r - N_LIT) * 64 + lane] = f2bf(hw[r * 68 + lane]);
        }
    }
}

// ---------------------------------------------------------------- X = h_lit @ Wc_bot (MFMA, fp32 in -> bf16 out)
__global__ __launch_bounds__(256, 4) void gemmX_kernel(
    const float* __restrict__ in, const float* __restrict__ W,
    unsigned short* __restrict__ out) {
    __shared__ __align__(16) unsigned short Bp[8 * 64 * 8];
    __shared__ float stage[4][16 * 66];
    int t = threadIdx.x;
    for (int idx = t; idx < 8 * 64 * 8; idx += 256) {
        int i = idx & 7, ln = (idx >> 3) & 63, fid = idx >> 9;
        int ks = fid >> 2, nt = fid & 3;
        Bp[idx] = f2bf(W[(ks * 32 + ((ln >> 4) << 3) + i) * 64 + nt * 16 + (ln & 15)]);
    }
    __syncthreads();
    int w = t >> 6, lane = t & 63;
    int c = lane & 15, q = lane >> 4;
    bf16x8 Bf[8];
    #pragma unroll
    for (int f = 0; f < 8; ++f) Bf[f] = *(const bf16x8*)&Bp[(f * 64 + lane) * 8];
    float* ms = stage[w];
    int nwaves = gridDim.x * 4;
    int wid = blockIdx.x * 4 + w;
    for (int tile = wid; tile < N_LIT / 16; tile += nwaves) {
        int row0 = tile * 16;
        const float* ap = in + (size_t)(row0 + c) * 64 + q * 8;
        bf16x8 A0, A1;
        #pragma unroll
        for (int i = 0; i < 8; ++i) {
            A0[i] = (short)f2bf(ap[i]);
            A1[i] = (short)f2bf(ap[32 + i]);
        }
        f32x4 acc[4];
        #pragma unroll
        for (int nt = 0; nt < 4; ++nt) {
            acc[nt] = (f32x4){0.f, 0.f, 0.f, 0.f};
            acc[nt] = __builtin_amdgcn_mfma_f32_16x16x32_bf16(A0, Bf[nt], acc[nt], 0, 0, 0);
            acc[nt] = __builtin_amdgcn_mfma_f32_16x16x32_bf16(A1, Bf[4 + nt], acc[nt], 0, 0, 0);
        }
        #pragma unroll
        for (int nt = 0; nt < 4; ++nt)
            #pragma unroll
            for (int rg = 0; rg < 4; ++rg)
                ms[(q * 4 + rg) * 66 + nt * 16 + c] = acc[nt][rg];
        for (int r = 0; r < 16; ++r)
            out[(size_t)(row0 + r) * 64 + lane] = f2bf(ms[r * 66 + lane]);
    }
}

// ---------------------------------------------------------------- clause update (MFMA + fused gather, in-place bf16)
// z_new[c] = (silu?(z[c]) @ Wc_top + bc) + inv[c] * sum_e X[lit[e]]
__global__ __launch_bounds__(256, 4) void cls_update_kernel(
    unsigned short* __restrict__ h_cls, const unsigned short* __restrict__ X,
    const int* __restrict__ rp, const int* __restrict__ lits,
    const float* __restrict__ inv_deg, const float* __restrict__ W,
    const float* __restrict__ b, int silu_in) {
    __shared__ __align__(16) unsigned short Bp[8 * 64 * 8];
    __shared__ float bs[64];
    __shared__ float stage[4][16 * 66];
    int t = threadIdx.x;
    for (int idx = t; idx < 8 * 64 * 8; idx += 256) {
        int i = idx & 7, ln = (idx >> 3) & 63, fid = idx >> 9;
        int ks = fid >> 2, nt = fid & 3;
        Bp[idx] = f2bf(W[(ks * 32 + ((ln >> 4) << 3) + i) * 64 + nt * 16 + (ln & 15)]);
    }
    if (t < 64) bs[t] = b[t];
    __syncthreads();
    int w = t >> 6, lane = t & 63;
    int c = lane & 15, q = lane >> 4;
    bf16x8 Bf[8];
    #pragma unroll
    for (int f = 0; f < 8; ++f) Bf[f] = *(const bf16x8*)&Bp[(f * 64 + lane) * 8];
    float* ms = stage[w];
    int nwaves = gridDim.x * 4;
    int wid = blockIdx.x * 4 + w;
    for (int tile = wid; tile < N_CLS / 16; tile += nwaves) {
        int row0 = tile * 16;
        const unsigned short* ap = h_cls + (size_t)(row0 + c) * 64 + q * 8;
        bf16x8 A0 = *(const bf16x8*)(ap);
        bf16x8 A1 = *(const bf16x8*)(ap + 32);
        if (silu_in) {
            #pragma unroll
            for (int i = 0; i < 8; ++i) {
                A0[i] = (short)f2bf(silu_f(bf2f((unsigned short)A0[i])));
                A1[i] = (short)f2bf(silu_f(bf2f((unsigned short)A1[i])));
            }
        }
        f32x4 acc[4];
        #pragma unroll
        for (int nt = 0; nt < 4; ++nt) {
            float bv = bs[nt * 16 + c];
            acc[nt] = (f32x4){bv, bv, bv, bv};
            acc[nt] = __builtin_amdgcn_mfma_f32_16x16x32_bf16(A0, Bf[nt], acc[nt], 0, 0, 0);
            acc[nt] = __builtin_amdgcn_mfma_f32_16x16x32_bf16(A1, Bf[4 + nt], acc[nt], 0, 0, 0);
        }
        // fused mean-gather of X along clause rows; lane = channel (coalesced 128B rows)
        for (int r = 0; r < 16; ++r) {
            int row = row0 + r;
            int e0 = rp[row], e1 = rp[row + 1];
            float g0 = 0.f, g1 = 0.f;
            int e = e0;
            for (; e + 1 < e1; e += 2) {
                g0 += bf2f(X[(size_t)lits[e] * 64 + lane]);
                g1 += bf2f(X[(size_t)lits[e + 1] * 64 + lane]);
            }
            if (e < e1) g0 += bf2f(X[(size_t)lits[e] * 64 + lane]);
            ms[r * 66 + lane] = (g0 + g1) * inv_deg[row];
        }
        #pragma unroll
        for (int nt = 0; nt < 4; ++nt)
            #pragma unroll
            for (int rg = 0; rg < 4; ++rg)
                ms[(q * 4 + rg) * 66 + nt * 16 + c] += acc[nt][rg];
        for (int r = 0; r < 16; ++r)
            h_cls[(size_t)(row0 + r) * 64 + lane] = f2bf(ms[r * 66 + lane]);
    }
}

// ---------------------------------------------------------------- lit-side gather (standalone, no LDS)
__global__ __launch_bounds__(256) void gather_lit_kernel(
    const unsigned short* __restrict__ h_cls, const int* __restrict__ rp,
    const int* __restrict__ clss, const float* __restrict__ inv_deg,
    unsigned short* __restrict__ m_out) {
    int nw = (gridDim.x * blockDim.x) >> 6;
    int wid = (blockIdx.x * blockDim.x + threadIdx.x) >> 6;
    int lane = threadIdx.x & 63;
    for (int row = wid; row < N_LIT; row += nw) {
        int e0 = rp[row], e1 = rp[row + 1];
        float g0 = 0.f, g1 = 0.f;
        int e = e0;
        for (; e + 1 < e1; e += 2) {
            int c0 = clss[e], c1 = clss[e + 1];
            g0 += silu_f(bf2f(h_cls[(size_t)c0 * 64 + lane]));
            g1 += silu_f(bf2f(h_cls[(size_t)c1 * 64 + lane]));
        }
        if (e < e1) g0 += silu_f(bf2f(h_cls[(size_t)clss[e] * 64 + lane]));
        m_out[(size_t)row * 64 + lane] = f2bf((g0 + g1) * inv_deg[row]);
    }
}

// ---------------------------------------------------------------- literal update (MFMA, in-place fp32)
// h[row] = silu([h[row], m[row], h[row^1]] @ W + b); K=192 -> 6 ksteps, 24 B frags in regs
__global__ __launch_bounds__(256, 3) void lit_update_kernel(
    float* __restrict__ h, const unsigned short* __restrict__ m,
    const float* __restrict__ W, const float* __restrict__ b) {
    __shared__ __align__(16) unsigned short Bp[24 * 64 * 8];   // 24 KB
    __shared__ float bs[64];
    __shared__ float stage[4][16 * 66];
    int t = threadIdx.x;
    for (int idx = t; idx < 24 * 64 * 8; idx += 256) {
        int i = idx & 7, ln = (idx >> 3) & 63, fid = idx >> 9;
        int ks = fid >> 2, nt = fid & 3;
        Bp[idx] = f2bf(W[(ks * 32 + ((ln >> 4) << 3) + i) * 64 + nt * 16 + (ln & 15)]);
    }
    if (t < 64) bs[t] = b[t];
    __syncthreads();
    int w = t >> 6, lane = t & 63;
    int c = lane & 15, q = lane >> 4;
    bf16x8 Bf[24];
    #pragma unroll
    for (int f = 0; f < 24; ++f) Bf[f] = *(const bf16x8*)&Bp[(f * 64 + lane) * 8];
    float* ms = stage[w];
    int nwaves = gridDim.x * 4;
    int wid = blockIdx.x * 4 + w;
    for (int tile = wid; tile < N_LIT / 16; tile += nwaves) {
        int row0 = tile * 16;
        bf16x8 A[6];
        const float* hp = h + (size_t)(row0 + c) * 64 + q * 8;
        const float* hf = h + (size_t)((row0 + c) ^ 1) * 64 + q * 8;
        const unsigned short* mp = m + (size_t)(row0 + c) * 64 + q * 8;
        #pragma unroll
        for (int i = 0; i < 8; ++i) {
            A[0][i] = (short)f2bf(hp[i]);
            A[1][i] = (short)f2bf(hp[32 + i]);
            A[4][i] = (short)f2bf(hf[i]);
            A[5][i] = (short)f2bf(hf[32 + i]);
        }
        A[2] = *(const bf16x8*)(mp);
        A[3] = *(const bf16x8*)(mp + 32);
        f32x4 acc[4];
        #pragma unroll
        for (int nt = 0; nt < 4; ++nt) {
            float bv = bs[nt * 16 + c];
            acc[nt] = (f32x4){bv, bv, bv, bv};
            #pragma unroll
            for (int ks = 0; ks < 6; ++ks)
                acc[nt] = __builtin_amdgcn_mfma_f32_16x16x32_bf16(A[ks], Bf[ks * 4 + nt], acc[nt], 0, 0, 0);
        }
        #pragma unroll
        for (int nt = 0; nt < 4; ++nt)
            #pragma unroll
            for (int rg = 0; rg < 4; ++rg)
                ms[(q * 4 + rg) * 66 + nt * 16 + c] = silu_f(acc[nt][rg]);
        for (int r = 0; r < 16; ++r)
            h[(size_t)(row0 + r) * 64 + lane] = ms[r * 66 + lane];
    }
}

// ---------------------------------------------------------------- readout stage 1 (fp32 VALU -> bf16 hid)
__global__ __launch_bounds__(256) void var_hidden_kernel(
    const float* __restrict__ h_var, const float* __restrict__ W,
    const float* __restrict__ b, int colofs, unsigned short* __restrict__ hid) {
    __shared__ float Ws[128 * 64];
    __shared__ float bs[64];
    __shared__ float rs[16 * 128];
    int t = threadIdx.x;
    for (int i = t; i < 128 * 64; i += 256) {
        int k = i >> 6, j = i & 63;
        Ws[i] = W[k * 128 + colofs + j];
    }
    if (t < 64) bs[t] = b[colofs + t];
    __syncthreads();
    const int ntiles = NVAR / 16;   // 6250
    int w = t >> 6, j = t & 63;
    for (int tile = blockIdx.x; tile < ntiles; tile += gridDim.x) {
        int row0 = tile * 16;
        for (int i = t; i < 2048; i += 256) rs[i] = h_var[(size_t)row0 * 128 + i];
        __syncthreads();
        float acc0 = bs[j], acc1 = bs[j], acc2 = bs[j], acc3 = bs[j];
        const float* r0 = &rs[(w * 4 + 0) * 128];
        const float* r1 = &rs[(w * 4 + 1) * 128];
        const float* r2 = &rs[(w * 4 + 2) * 128];
        const float* r3 = &rs[(w * 4 + 3) * 128];
        #pragma unroll 4
        for (int k = 0; k < 128; k += 4) {
            float w0 = Ws[k * 64 + j], w1v = Ws[(k + 1) * 64 + j];
            float w2v = Ws[(k + 2) * 64 + j], w3v = Ws[(k + 3) * 64 + j];
            float4 a;
            a = *(const float4*)(r0 + k); acc0 += a.x * w0 + a.y * w1v + a.z * w2v + a.w * w3v;
            a = *(const float4*)(r1 + k); acc1 += a.x * w0 + a.y * w1v + a.z * w2v + a.w * w3v;
            a = *(const float4*)(r2 + k); acc2 += a.x * w0 + a.y * w1v + a.z * w2v + a.w * w3v;
            a = *(const float4*)(r3 + k); acc3 += a.x * w0 + a.y * w1v + a.z * w2v + a.w * w3v;
        }
        int row = row0 + w * 4;
        hid[(size_t)(row + 0) * 128 + colofs + j] = f2bf(silu_f(acc0));
        hid[(size_t)(row + 1) * 128 + colofs + j] = f2bf(silu_f(acc1));
        hid[(size_t)(row + 2) * 128 + colofs + j] = f2bf(silu_f(acc2));
        hid[(size_t)(row + 3) * 128 + colofs + j] = f2bf(silu_f(acc3));
        __syncthreads();
    }
}

// ---------------------------------------------------------------- readout stage 2
__global__ __launch_bounds__(256) void out2_kernel(
    const unsigned short* __restrict__ hid, const float* __restrict__ w2,
    const float* __restrict__ b2, float* __restrict__ out) {
    int nw = (gridDim.x * blockDim.x) >> 6;
    int wid = (blockIdx.x * blockDim.x + threadIdx.x) >> 6;
    int lane = threadIdx.x & 63;
    float w00 = w2[lane * 2 + 0], w01 = w2[lane * 2 + 1];
    float w10 = w2[(lane + 64) * 2 + 0], w11 = w2[(lane + 64) * 2 + 1];
    for (int row = wid; row < NVAR; row += nw) {
        float h0 = bf2f(hid[(size_t)row * 128 + lane]);
        float h1 = bf2f(hid[(size_t)row * 128 + 64 + lane]);
        float p0 = h0 * w00 + h1 * w10;
        float p1 = h0 * w01 + h1 * w11;
        #pragma unroll
        for (int off = 32; off > 0; off >>= 1) {
            p0 += __shfl_down(p0, off);
            p1 += __shfl_down(p1, off);
        }
        if (lane == 0) {
            out[(size_t)row * 2 + 0] = p0 + b2[0];
            out[(size_t)row * 2 + 1] = p1 + b2[1];
        }
    }
}

// ---------------------------------------------------------------- launch
extern "C" void kernel_launch(void* const* d_in, const int* in_sizes, int n_in,
                              void* d_out, int out_size, void* d_ws, size_t ws_size,
                              hipStream_t stream) {
    const float* x_lit  = (const float*)d_in[0];
    const float* x_cls  = (const float*)d_in[1];
    const int* edge_lit = (const int*)d_in[2];
    const int* edge_cls = (const int*)d_in[3];
    const float* enc_w1 = (const float*)d_in[4];
    const float* enc_b1 = (const float*)d_in[5];
    const float* enc_w2 = (const float*)d_in[6];
    const float* enc_b2 = (const float*)d_in[7];
    const float* Wc     = (const float*)d_in[8];    // [4][128][64]
    const float* bc     = (const float*)d_in[9];
    const float* Wl     = (const float*)d_in[10];   // [4][192][64]
    const float* bl     = (const float*)d_in[11];
    const float* out_w1 = (const float*)d_in[12];   // [128][128]
    const float* out_b1 = (const float*)d_in[13];
    const float* out_w2 = (const float*)d_in[14];   // [128][2]
    const float* out_b2 = (const float*)d_in[15];
    float* y = (float*)d_out;

    // ---- workspace carve (each region 256B aligned), ~211 MB total ----
    const size_t SZ_HLIT = (size_t)N_LIT * 64;
    const size_t SZ_HCLS = (size_t)N_CLS * 64;
    char* p = (char*)d_ws;
    auto take = [&](size_t bytes) -> char* {
        char* r = p; p += (bytes + 255) & ~(size_t)255; return r;
    };
    float*          h_lit      = (float*)take(SZ_HLIT * 4);
    unsigned short* h_cls      = (unsigned short*)take(SZ_HCLS * 2);
    unsigned short* X          = (unsigned short*)take(SZ_HLIT * 2);
    float*          inv_cls    = (float*)take((size_t)N_CLS * 4);
    float*          inv_lit    = (float*)take((size_t)N_LIT * 4);
    int*            row_ptr_cls= (int*)take((size_t)(N_CLS + 1) * 4);
    int*            row_ptr_lit= (int*)take((size_t)(N_LIT + 1) * 4);
    int*            cur_cls    = (int*)take((size_t)(N_CLS + N_LIT) * 4);
    int*            cur_lit    = cur_cls + N_CLS;
    int*            lit_by_cls = (int*)take((size_t)NEDGE * 4);
    int*            cls_by_lit = (int*)take((size_t)NEDGE * 4);
    int*            partA      = (int*)take(1024 * 4);
    int*            partB      = (int*)take(1024 * 4);
    size_t need = (size_t)(p - (char*)d_ws);

    dim3 B(256);

    if (ws_size < need) {
        float mb = (float)((double)ws_size / (1024.0 * 1024.0));
        diag_kernel<<<256, B, 0, stream>>>(y, out_size, mb);
        return;
    }

    // ---- CSR build ----
    zero_int4_kernel<<<512, B, 0, stream>>>((int4*)cur_cls, (long)(N_CLS + N_LIT) / 4);
    deg_kernel<<<2048, B, 0, stream>>>(edge_lit, edge_cls, cur_lit, cur_cls);
    inv_deg_kernel<<<(N_CLS + 255) / 256, B, 0, stream>>>(cur_cls, inv_cls, N_CLS);
    inv_deg_kernel<<<(N_LIT + 255) / 256, B, 0, stream>>>(cur_lit, inv_lit, N_LIT);
    int nbc = (N_CLS + 1023) / 1024;
    int nbl = (N_LIT + 1023) / 1024;
    scan_partial_kernel<<<nbc, B, 0, stream>>>(cur_cls, N_CLS, partA);
    scan_root_kernel<<<1, 1024, 0, stream>>>(partA, nbc);
    scan_final_kernel<<<nbc, B, 0, stream>>>(cur_cls, partA, row_ptr_cls, N_CLS);
    scan_partial_kernel<<<nbl, B, 0, stream>>>(cur_lit, N_LIT, partB);
    scan_root_kernel<<<1, 1024, 0, stream>>>(partB, nbl);
    scan_final_kernel<<<nbl, B, 0, stream>>>(cur_lit, partB, row_ptr_lit, N_LIT);
    tail_kernel<<<1, 64, 0, stream>>>(row_ptr_cls, row_ptr_lit);
    copy_int_kernel<<<1024, B, 0, stream>>>(cur_cls, row_ptr_cls, N_CLS);
    copy_int_kernel<<<512, B, 0, stream>>>(cur_lit, row_ptr_lit, N_LIT);
    fill_csr_kernel<<<2048, B, 0, stream>>>(edge_lit, edge_cls, cur_cls, cur_lit,
                                            lit_by_cls, cls_by_lit);

    // ---- encoder ----
    encoder_kernel<<<2048, B, 0, stream>>>(x_lit, x_cls, enc_w1, enc_b1, enc_w2, enc_b2,
                                           h_lit, h_cls);
    // state: h_lit post-activation fp32; h_cls pre-activation bf16 (layer 0 consumes raw)

    for (int l = 0; l < 4; ++l) {
        const float* Wc_l = Wc + (size_t)l * 128 * 64;
        const float* Wl_l = Wl + (size_t)l * 192 * 64;
        gemmX_kernel<<<1024, B, 0, stream>>>(h_lit, Wc_l + 64 * 64, X);
        cls_update_kernel<<<2048, B, 0, stream>>>(h_cls, X, row_ptr_cls, lit_by_cls,
                                                  inv_cls, Wc_l, bc + l * 64, l > 0);
        gather_lit_kernel<<<4096, B, 0, stream>>>(h_cls, row_ptr_lit, cls_by_lit,
                                                  inv_lit, X);
        lit_update_kernel<<<1024, B, 0, stream>>>(h_lit, X, Wl_l, bl + l * 64);
    }

    // ---- readout (fp32 path for accuracy; hid reuses X) ----
    var_hidden_kernel<<<4096, B, 0, stream>>>(h_lit, out_w1, out_b1, 0, X);
    var_hidden_kernel<<<4096, B, 0, stream>>>(h_lit, out_w1, out_b1, 64, X);
    out2_kernel<<<2048, B, 0, stream>>>(X, out_w2, out_b2, y);
}